// Round 4
// baseline (5363.540 us; speedup 1.0000x reference)
//
#include <hip/hip_runtime.h>
#include <math.h>

#define NN 50000
#define EE 1600000
#define FN 92
#define FE 41
#define CC 128
#define LL 3
#define GG 256
#define ZDIM 297   // 2C + F_EDGE

typedef __attribute__((ext_vector_type(8))) short s8v;   // 8 bf16 (4 VGPRs)
typedef __attribute__((ext_vector_type(4))) float f4v;   // MFMA C/D

__device__ __forceinline__ float softplus_f(float x) {
    float e = __expf(-fabsf(x));
    return fmaxf(x, 0.0f) + __logf(1.0f + e);
}
__device__ __forceinline__ float sigmoid_f(float x) {
    return __builtin_amdgcn_rcpf(1.0f + __expf(-x));
}
__device__ __forceinline__ unsigned short f2bf(float x) {   // RNE fp32->bf16
    unsigned u = __builtin_bit_cast(unsigned, x);
    unsigned r = u + 0x7fffu + ((u >> 16) & 1u);
    return (unsigned short)(r >> 16);
}
__device__ __forceinline__ float bflo2f(unsigned u) {  // low ushort as bf16
    return __builtin_bit_cast(float, u << 16);
}
__device__ __forceinline__ float bfhi2f(unsigned u) {  // high ushort as bf16
    return __builtin_bit_cast(float, u & 0xffff0000u);
}

// ---------------------------------------------------------------------------
// fp32 tiled GEMM: C = act(A[M][lda](K used) @ B[Kpad][NC] + bias)
// OUTBF=1: write bf16 (pairs of adjacent columns packed into uint) to C.
// ---------------------------------------------------------------------------
template<int ACT, int OUTBF>
__global__ __launch_bounds__(256)
void gemm_rt(const float* __restrict__ A, const float* __restrict__ B,
             float* __restrict__ C, const float* __restrict__ bias,
             int M, int K, int lda, int NC) {
    __shared__ float As[32][68];
    __shared__ float Bs[32 * 128];
    int tid = threadIdx.x;
    int colTiles = NC >> 7;
    int rowTile = blockIdx.x / colTiles;
    int colTile = blockIdx.x - rowTile * colTiles;
    int row0 = rowTile * 64;
    int c0 = colTile * 128;
    int ty = tid >> 5;
    int tx = tid & 31;

    float acc[8][4];
#pragma unroll
    for (int i = 0; i < 8; i++)
#pragma unroll
        for (int j = 0; j < 4; j++) acc[i][j] = 0.f;

    int nChunks = (K + 31) >> 5;
    for (int ch = 0; ch < nChunks; ch++) {
        int k0 = ch << 5;
#pragma unroll
        for (int t = 0; t < 8; t++) {
            int idx = tid + t * 256;
            int r = idx >> 5;
            int kk = idx & 31;
            int grow = row0 + r;
            int gk = k0 + kk;
            float v = 0.f;
            if (grow < M && gk < K) v = A[(long)grow * lda + gk];
            As[kk][r] = v;
        }
        const float* Bg = B + (long)k0 * NC + c0;
#pragma unroll
        for (int t = 0; t < 4; t++) {
            int f4 = tid + t * 256;
            int kk = f4 >> 5;
            int j = (f4 & 31) << 2;
            float4 v = *(const float4*)(Bg + (long)kk * NC + j);
            *(float4*)(&Bs[kk * 128 + j]) = v;
        }
        __syncthreads();
#pragma unroll
        for (int kk = 0; kk < 32; kk++) {
            float4 a0 = *(const float4*)(&As[kk][ty * 8]);
            float4 a1 = *(const float4*)(&As[kk][ty * 8 + 4]);
            float4 b  = *(const float4*)(&Bs[kk * 128 + tx * 4]);
            float av[8] = {a0.x, a0.y, a0.z, a0.w, a1.x, a1.y, a1.z, a1.w};
            float bv[4] = {b.x, b.y, b.z, b.w};
#pragma unroll
            for (int i = 0; i < 8; i++)
#pragma unroll
                for (int j = 0; j < 4; j++)
                    acc[i][j] = fmaf(av[i], bv[j], acc[i][j]);
        }
        __syncthreads();
    }
    float bv[4] = {0.f, 0.f, 0.f, 0.f};
    if (bias) {
#pragma unroll
        for (int j = 0; j < 4; j++) bv[j] = bias[c0 + tx * 4 + j];
    }
#pragma unroll
    for (int i = 0; i < 8; i++) {
        int grow = row0 + ty * 8 + i;
        if (grow < M) {
            float r0 = acc[i][0] + bv[0];
            float r1 = acc[i][1] + bv[1];
            float r2 = acc[i][2] + bv[2];
            float r3 = acc[i][3] + bv[3];
            if (ACT) { r0 = softplus_f(r0); r1 = softplus_f(r1);
                       r2 = softplus_f(r2); r3 = softplus_f(r3); }
            if (OUTBF) {
                unsigned u0 = (unsigned)f2bf(r0) | ((unsigned)f2bf(r1) << 16);
                unsigned u1 = (unsigned)f2bf(r2) | ((unsigned)f2bf(r3) << 16);
                uint2 val; val.x = u0; val.y = u1;
                unsigned short* Cb = (unsigned short*)C;
                *(uint2*)(Cb + (long)grow * NC + c0 + tx * 4) = val;
            } else {
                float4 o; o.x = r0; o.y = r1; o.z = r2; o.w = r3;
                *(float4*)(&C[(long)grow * NC + c0 + tx * 4]) = o;
            }
        }
    }
}

// WB[k][j], j=0..511: g=j&1 (0=f/Wf, 1=s/Ws); pos=j>>1; blk=pos>>7 (0=dst->x_i
// cols 0..127, 1=src->x_j cols 128..255); c=pos&127.
__global__ void build_WB(const float* __restrict__ Wf, const float* __restrict__ Ws,
                         float* __restrict__ WB) {
    int idx = blockIdx.x * blockDim.x + threadIdx.x;
    if (idx >= 128 * 512) return;
    int k = idx >> 9;
    int j = idx & 511;
    int g = j & 1;
    int pos = j >> 1;
    int blk = pos >> 7;
    int c = pos & 127;
    const float* W = g ? Ws : Wf;
    WB[idx] = W[c * ZDIM + blk * 128 + k];
}

// WE[l][g][c][k] bf16, k<41: edge-weight col, k==41: bias, else 0. K padded to 64.
__global__ void build_WE(const float* __restrict__ Wf, const float* __restrict__ Ws,
                         const float* __restrict__ bf, const float* __restrict__ bs,
                         unsigned short* __restrict__ WE) {
    int idx = blockIdx.x * blockDim.x + threadIdx.x;
    if (idx >= LL * 2 * 128 * 64) return;
    int k = idx & 63;
    int c = (idx >> 6) & 127;
    int g = (idx >> 13) & 1;
    int l = idx >> 14;
    const float* W = g ? Ws : Wf;
    const float* b = g ? bs : bf;
    float v = 0.f;
    if (k < FE) v = W[((long)l * 128 + c) * ZDIM + 256 + k];
    else if (k == FE) v = b[l * 128 + c];
    WE[idx] = f2bf(v);
}

// WT[Kpad][C] = W[C][K]^T zero-padded
__global__ void transpose_pad(const float* __restrict__ W, float* __restrict__ WT,
                              int C_, int K_, int Kpad) {
    int idx = blockIdx.x * blockDim.x + threadIdx.x;
    if (idx >= Kpad * C_) return;
    int k = idx / C_;
    int c = idx - k * C_;
    WT[idx] = (k < K_) ? W[c * K_ + k] : 0.f;
}

// ---------------------------------------------------------------------------
// Counting sort of edges by dst (static graph, reused for all 3 layers).
// ---------------------------------------------------------------------------
__global__ void hist_dst(const int* __restrict__ dstI, int* __restrict__ deg) {
    int idx = blockIdx.x * 256 + threadIdx.x;
    if (idx < EE) atomicAdd(&deg[dstI[idx]], 1);
}

__global__ void scan_block_sums(const int* __restrict__ deg, int* __restrict__ bsum) {
    __shared__ int sh[256];
    int i = blockIdx.x * 256 + threadIdx.x;
    sh[threadIdx.x] = (i < NN) ? deg[i] : 0;
    __syncthreads();
    for (int s = 128; s > 0; s >>= 1) {
        if (threadIdx.x < s) sh[threadIdx.x] += sh[threadIdx.x + s];
        __syncthreads();
    }
    if (threadIdx.x == 0) bsum[blockIdx.x] = sh[0];
}

__global__ void scan_partials_k(int* __restrict__ bsum, int nb) {
    __shared__ int sh[256];
    int t = threadIdx.x;
    int v = (t < nb) ? bsum[t] : 0;
    sh[t] = v;
    __syncthreads();
    for (int off = 1; off < 256; off <<= 1) {
        int u = (t >= off) ? sh[t - off] : 0;
        __syncthreads();
        sh[t] += u;
        __syncthreads();
    }
    if (t < nb) bsum[t] = sh[t] - v;   // exclusive block offsets
}

__global__ void scan_apply(const int* __restrict__ deg, const int* __restrict__ bsum,
                           int* __restrict__ rowptr, int* __restrict__ cursor) {
    __shared__ int sh[256];
    int i = blockIdx.x * 256 + threadIdx.x;
    int t = threadIdx.x;
    int v = (i < NN) ? deg[i] : 0;
    int orig = v;
    sh[t] = v;
    __syncthreads();
    for (int off = 1; off < 256; off <<= 1) {
        int u = (t >= off) ? sh[t - off] : 0;
        __syncthreads();
        sh[t] += u;
        __syncthreads();
    }
    int ex = sh[t] - orig + bsum[blockIdx.x];
    if (i < NN) { rowptr[i] = ex; cursor[i] = ex; }
    if (i == NN - 1) rowptr[NN] = ex + orig;   // == EE
}

// srcS[p] = src id of slot p; eOf[p] = original edge index of slot p.
__global__ void scatter_edges(const int* __restrict__ srcI, const int* __restrict__ dstI,
                              int* __restrict__ cursor, int* __restrict__ srcS,
                              int* __restrict__ eOf) {
    int idx = blockIdx.x * 256 + threadIdx.x;
    if (idx >= EE) return;
    int d = dstI[idx];
    int p = atomicAdd(&cursor[d], 1);
    srcS[p] = srcI[idx];
    eOf[p] = idx;
}

// eaB[slot][48] bf16 A-fragment rows in dst-sorted order: k<41 = ea, k==41 = 1.0
// (bias), 42..47 = 0. Gather-read (random 164B rows), coalesced sequential write.
__global__ void pack_ea(const float* __restrict__ ea, const int* __restrict__ eOf,
                        unsigned* __restrict__ eaBu) {
    int idx = blockIdx.x * 256 + threadIdx.x;
    if (idx >= EE * 24) return;
    int p = idx / 24;
    int k2 = idx - p * 24;
    int k = k2 * 2;
    int e = eOf[p];
    const float* row = ea + (long)e * FE;
    float v0 = 0.f, v1 = 0.f;
    if (k < FE) v0 = row[k];
    if (k + 1 < FE) v1 = row[k + 1];
    else if (k + 1 == FE) v1 = 1.0f;
    eaBu[idx] = (unsigned)f2bf(v0) | ((unsigned)f2bf(v1) << 16);
}

// ---------------------------------------------------------------------------
// Per-dst-node fused edge kernel, PERSISTENT grid + spill-free inner loop.
// NOTE: plain __launch_bounds__(256) — the (256,3) min-occupancy clause capped
// the allocator at 84 VGPR and spilled accf/accs to scratch (R2/R3: +3 GB of
// scratch traffic per dispatch). R1 proved this body compiles to 136 VGPR with
// zero spills, which the HW runs at 3 waves/SIMD = 3 blocks/CU anyway.
// ---------------------------------------------------------------------------
__global__ __launch_bounds__(256)
void edge_node(const unsigned* __restrict__ Pu,             // [N][256] uint pairs
               const unsigned short* __restrict__ eaB,      // [E+16][48] bf16 sorted
               const int* __restrict__ srcS,                // [E+16] sorted src ids
               const int* __restrict__ rowptr,              // [N+1]
               const unsigned short* __restrict__ WE,       // [2][128][64] this layer
               float* __restrict__ out) {
    const int lane = threadIdx.x & 63;
    const int quad = lane >> 4;
    const int l16 = lane & 15;
    const int nW = gridDim.x * 4;
    const unsigned short* WEf = WE;
    const unsigned short* WEs = WE + 128 * 64;

    for (int n = blockIdx.x * 4 + (threadIdx.x >> 6); n < NN; n += nW) {
        int r0 = rowptr[n], r1 = rowptr[n + 1];

        // dst projection row (x_i term), folded into MFMA C-init
        unsigned pd[8];
        const unsigned* pdr = Pu + (size_t)n * 256;
#pragma unroll
        for (int nt = 0; nt < 8; nt++) pd[nt] = pdr[nt * 16 + l16];

        float aggv[8];
#pragma unroll
        for (int nt = 0; nt < 8; nt++) aggv[nt] = 0.f;

        for (int base = r0; base < r1; base += 16) {
            int rows = r1 - base;
            if (rows > 16) rows = 16;

            const unsigned short* ar = eaB + (size_t)(base + l16) * 48;
            s8v a0 = *(const s8v*)(ar + quad * 8);                 // k = 0..31
            s8v a1 = {0, 0, 0, 0, 0, 0, 0, 0};
            if (quad < 2) a1 = *(const s8v*)(ar + 32 + quad * 8);  // k = 32..47
            int s16 = srcS[base + l16];

            f4v accf[8], accs[8];
#pragma unroll
            for (int nt = 0; nt < 8; nt++) {
                int crow = nt * 16 + l16;
                float fdf = bflo2f(pd[nt]);
                float fds = bfhi2f(pd[nt]);
                f4v zf = {fdf, fdf, fdf, fdf};
                f4v zs = {fds, fds, fds, fds};
                s8v bf0 = *(const s8v*)(WEf + crow * 64 + quad * 8);
                s8v bf1 = *(const s8v*)(WEf + crow * 64 + 32 + quad * 8);
                zf = __builtin_amdgcn_mfma_f32_16x16x32_bf16(a0, bf0, zf, 0, 0, 0);
                zf = __builtin_amdgcn_mfma_f32_16x16x32_bf16(a1, bf1, zf, 0, 0, 0);
                accf[nt] = zf;
                s8v bs0 = *(const s8v*)(WEs + crow * 64 + quad * 8);
                s8v bs1 = *(const s8v*)(WEs + crow * 64 + 32 + quad * 8);
                zs = __builtin_amdgcn_mfma_f32_16x16x32_bf16(a0, bs0, zs, 0, 0, 0);
                zs = __builtin_amdgcn_mfma_f32_16x16x32_bf16(a1, bs1, zs, 0, 0, 0);
                accs[nt] = zs;
            }

#pragma unroll
            for (int r = 0; r < 4; r++) {
                int el = quad * 4 + r;                 // edge row in D layout
                int sv = __shfl(s16, el);
                const unsigned* ps = Pu + (size_t)sv * 256 + 128;
#pragma unroll
                for (int nt = 0; nt < 8; nt++) {
                    unsigned u = ps[nt * 16 + l16];
                    float f = accf[nt][r] + bflo2f(u);
                    float s = accs[nt][r] + bfhi2f(u);
                    float m = sigmoid_f(f) * softplus_f(s);
                    aggv[nt] += (el < rows) ? m : 0.f;
                }
            }
        }

        // cross-quad reduce: sum the 16 edge rows per channel
#pragma unroll
        for (int nt = 0; nt < 8; nt++) {
            float v = aggv[nt];
            v += __shfl_xor(v, 16);
            v += __shfl_xor(v, 32);
            aggv[nt] = v;
        }
        // fused residual + softplus; lane i writes channels i and 64+i (coalesced)
        float vlo = quad == 0 ? aggv[0] : quad == 1 ? aggv[1] : quad == 2 ? aggv[2] : aggv[3];
        float vhi = quad == 0 ? aggv[4] : quad == 1 ? aggv[5] : quad == 2 ? aggv[6] : aggv[7];
        float* orow = out + (size_t)n * CC;
        orow[lane]      = softplus_f(orow[lane] + vlo);
        orow[64 + lane] = softplus_f(orow[64 + lane] + vhi);
    }
}

__global__ void pool_accum(const float* __restrict__ post, const int* __restrict__ batch,
                           float* __restrict__ sums, float* __restrict__ cnt) {
    int idx = blockIdx.x * blockDim.x + threadIdx.x;
    if (idx >= NN * CC) return;
    int n = idx >> 7;
    int c = idx & 127;
    int g = batch[n];
    atomicAdd(&sums[g * CC + c], post[idx]);
    if (c == 0) atomicAdd(&cnt[g], 1.0f);
}

__global__ void pool_head(const float* __restrict__ sums, const float* __restrict__ cnt,
                          const float* __restrict__ Wout, const float* __restrict__ bout,
                          float* __restrict__ y) {
    int g = blockIdx.x;
    int c = threadIdx.x;  // 128
    float v = sums[g * CC + c] / fmaxf(cnt[g], 1.0f) * Wout[c];
#pragma unroll
    for (int off = 32; off > 0; off >>= 1) v += __shfl_down(v, off);
    __shared__ float red[2];
    if ((c & 63) == 0) red[c >> 6] = v;
    __syncthreads();
    if (c == 0) y[g] = red[0] + red[1] + bout[0];
}

extern "C" void kernel_launch(void* const* d_in, const int* in_sizes, int n_in,
                              void* d_out, int out_size, void* d_ws, size_t ws_size,
                              hipStream_t stream) {
    const float* x      = (const float*)d_in[0];
    const int*   eidx   = (const int*)d_in[1];
    const float* ea     = (const float*)d_in[2];
    const int*   batch  = (const int*)d_in[3];
    const float* W_pre  = (const float*)d_in[4];
    const float* b_pre  = (const float*)d_in[5];
    const float* Wf     = (const float*)d_in[6];
    const float* bf     = (const float*)d_in[7];
    const float* Ws     = (const float*)d_in[8];
    const float* bs     = (const float*)d_in[9];
    const float* W_post = (const float*)d_in[10];
    const float* b_post = (const float*)d_in[11];
    const float* W_out  = (const float*)d_in[12];
    const float* b_out  = (const float*)d_in[13];
    float* y = (float*)d_out;

    const int* srcI = eidx;        // edge_index[0] = src (x_j)
    const int* dstI = eidx + EE;   // edge_index[1] = dst (x_i)

    // workspace layout (~245 MB)
    char* wp = (char*)d_ws;
    unsigned short* P_bf = (unsigned short*)wp; wp += (size_t)NN * 512 * 2;   // 51.2MB
    unsigned short* eaB  = (unsigned short*)wp; wp += (size_t)(EE + 16) * 48 * 2; // 153.6MB
    int* srcS   = (int*)wp; wp += (size_t)(EE + 16) * 4;                      // 6.4MB
    int* eOf    = (int*)wp; wp += (size_t)EE * 4;                             // 6.4MB
    float* out  = (float*)wp; wp += (size_t)NN * CC * 4;                      // 25.6MB
    float* WB   = (float*)wp; wp += 128 * 512 * 4;
    float* WT   = (float*)wp; wp += 128 * 128 * 4;
    float* sums = (float*)wp; wp += (size_t)GG * CC * 4;
    float* cnt  = (float*)wp; wp += GG * 4;
    unsigned short* WE = (unsigned short*)wp; wp += (size_t)LL * 2 * 128 * 64 * 2;
    int* deg    = (int*)wp; wp += (size_t)NN * 4;
    int* rowptr = (int*)wp; wp += (size_t)(NN + 1) * 4;
    int* cursor = (int*)wp; wp += (size_t)NN * 4;
    int* bsum   = (int*)wp; wp += 256 * 4;
    float* post = (float*)P_bf;             // reuse after layers

    int rowTiles = (NN + 63) / 64;
    int scanBlocks = (NN + 255) / 256;      // 196

    // pre-FC
    transpose_pad<<<(96 * 128 + 255) / 256, 256, 0, stream>>>(W_pre, WT, CC, FN, 96);
    gemm_rt<1, 0><<<rowTiles, 256, 0, stream>>>(x, WT, out, b_pre, NN, FN, FN, CC);

    build_WE<<<(LL * 2 * 128 * 64 + 255) / 256, 256, 0, stream>>>(Wf, Ws, bf, bs, WE);

    // ---- counting sort by dst + A-fragment pack (once, reused 3 layers) ----
    hipMemsetAsync(deg, 0, (size_t)NN * 4, stream);
    hist_dst<<<(EE + 255) / 256, 256, 0, stream>>>(dstI, deg);
    scan_block_sums<<<scanBlocks, 256, 0, stream>>>(deg, bsum);
    scan_partials_k<<<1, 256, 0, stream>>>(bsum, scanBlocks);
    scan_apply<<<scanBlocks, 256, 0, stream>>>(deg, bsum, rowptr, cursor);
    scatter_edges<<<(EE + 255) / 256, 256, 0, stream>>>(srcI, dstI, cursor, srcS, eOf);
    hipMemsetAsync(srcS + EE, 0, 16 * 4, stream);                 // tail pad: node 0
    hipMemsetAsync(eaB + (size_t)EE * 48, 0, 16 * 48 * 2, stream);// tail pad: zeros
    pack_ea<<<(EE * 24 + 255) / 256, 256, 0, stream>>>(ea, eOf, (unsigned*)eaB);

    for (int l = 0; l < LL; l++) {
        const float* Wfl = Wf + (size_t)l * CC * ZDIM;
        const float* Wsl = Ws + (size_t)l * CC * ZDIM;
        build_WB<<<(128 * 512 + 255) / 256, 256, 0, stream>>>(Wfl, Wsl, WB);
        gemm_rt<0, 1><<<rowTiles * 4, 256, 0, stream>>>(out, WB, (float*)P_bf,
                                                        nullptr, NN, CC, CC, 512);
        edge_node<<<768, 256, 0, stream>>>((const unsigned*)P_bf, eaB, srcS,
                                           rowptr, WE + (size_t)l * 2 * 128 * 64,
                                           out);
    }

    // post-FC
    transpose_pad<<<(128 * 128 + 255) / 256, 256, 0, stream>>>(W_post, WT, CC, CC, CC);
    gemm_rt<1, 0><<<rowTiles, 256, 0, stream>>>(out, WT, post, b_post, NN, CC, CC, CC);

    // global mean pool + head
    hipMemsetAsync(sums, 0, ((size_t)GG * CC + GG) * sizeof(float), stream);
    pool_accum<<<(NN * CC + 255) / 256, 256, 0, stream>>>(post, batch, sums, cnt);
    pool_head<<<GG, 128, 0, stream>>>(sums, cnt, W_out, b_out, y);
}

// Round 5
// 2811.954 us; speedup vs baseline: 1.9074x; 1.9074x over previous
//
#include <hip/hip_runtime.h>
#include <math.h>

#define NN 50000
#define EE 1600000
#define FN 92
#define FE 41
#define CC 128
#define LL 3
#define GG 256
#define ZDIM 297   // 2C + F_EDGE

typedef __attribute__((ext_vector_type(8))) short s8v;   // 8 bf16 (4 VGPRs)
typedef __attribute__((ext_vector_type(4))) float f4v;   // MFMA C/D

__device__ __forceinline__ float softplus_f(float x) {
    float e = __expf(-fabsf(x));
    return fmaxf(x, 0.0f) + __logf(1.0f + e);
}
__device__ __forceinline__ float sigmoid_f(float x) {
    return __builtin_amdgcn_rcpf(1.0f + __expf(-x));
}
__device__ __forceinline__ unsigned short f2bf(float x) {   // RNE fp32->bf16
    unsigned u = __builtin_bit_cast(unsigned, x);
    unsigned r = u + 0x7fffu + ((u >> 16) & 1u);
    return (unsigned short)(r >> 16);
}
__device__ __forceinline__ float bflo2f(unsigned u) {  // low ushort as bf16
    return __builtin_bit_cast(float, u << 16);
}
__device__ __forceinline__ float bfhi2f(unsigned u) {  // high ushort as bf16
    return __builtin_bit_cast(float, u & 0xffff0000u);
}
// component select; i is a compile-time constant after unrolling -> folds to mov
__device__ __forceinline__ unsigned u4c(const uint4& v, int i) {
    return i == 0 ? v.x : i == 1 ? v.y : i == 2 ? v.z : v.w;
}

// ---------------------------------------------------------------------------
// fp32 tiled GEMM: C = act(A[M][lda](K used) @ B[Kpad][NC] + bias)
// OUTBF=1: write bf16 (pairs of adjacent columns packed into uint) to C.
// ---------------------------------------------------------------------------
template<int ACT, int OUTBF>
__global__ __launch_bounds__(256)
void gemm_rt(const float* __restrict__ A, const float* __restrict__ B,
             float* __restrict__ C, const float* __restrict__ bias,
             int M, int K, int lda, int NC) {
    __shared__ float As[32][68];
    __shared__ float Bs[32 * 128];
    int tid = threadIdx.x;
    int colTiles = NC >> 7;
    int rowTile = blockIdx.x / colTiles;
    int colTile = blockIdx.x - rowTile * colTiles;
    int row0 = rowTile * 64;
    int c0 = colTile * 128;
    int ty = tid >> 5;
    int tx = tid & 31;

    float acc[8][4];
#pragma unroll
    for (int i = 0; i < 8; i++)
#pragma unroll
        for (int j = 0; j < 4; j++) acc[i][j] = 0.f;

    int nChunks = (K + 31) >> 5;
    for (int ch = 0; ch < nChunks; ch++) {
        int k0 = ch << 5;
#pragma unroll
        for (int t = 0; t < 8; t++) {
            int idx = tid + t * 256;
            int r = idx >> 5;
            int kk = idx & 31;
            int grow = row0 + r;
            int gk = k0 + kk;
            float v = 0.f;
            if (grow < M && gk < K) v = A[(long)grow * lda + gk];
            As[kk][r] = v;
        }
        const float* Bg = B + (long)k0 * NC + c0;
#pragma unroll
        for (int t = 0; t < 4; t++) {
            int f4 = tid + t * 256;
            int kk = f4 >> 5;
            int j = (f4 & 31) << 2;
            float4 v = *(const float4*)(Bg + (long)kk * NC + j);
            *(float4*)(&Bs[kk * 128 + j]) = v;
        }
        __syncthreads();
#pragma unroll
        for (int kk = 0; kk < 32; kk++) {
            float4 a0 = *(const float4*)(&As[kk][ty * 8]);
            float4 a1 = *(const float4*)(&As[kk][ty * 8 + 4]);
            float4 b  = *(const float4*)(&Bs[kk * 128 + tx * 4]);
            float av[8] = {a0.x, a0.y, a0.z, a0.w, a1.x, a1.y, a1.z, a1.w};
            float bv[4] = {b.x, b.y, b.z, b.w};
#pragma unroll
            for (int i = 0; i < 8; i++)
#pragma unroll
                for (int j = 0; j < 4; j++)
                    acc[i][j] = fmaf(av[i], bv[j], acc[i][j]);
        }
        __syncthreads();
    }
    float bv[4] = {0.f, 0.f, 0.f, 0.f};
    if (bias) {
#pragma unroll
        for (int j = 0; j < 4; j++) bv[j] = bias[c0 + tx * 4 + j];
    }
#pragma unroll
    for (int i = 0; i < 8; i++) {
        int grow = row0 + ty * 8 + i;
        if (grow < M) {
            float r0 = acc[i][0] + bv[0];
            float r1 = acc[i][1] + bv[1];
            float r2 = acc[i][2] + bv[2];
            float r3 = acc[i][3] + bv[3];
            if (ACT) { r0 = softplus_f(r0); r1 = softplus_f(r1);
                       r2 = softplus_f(r2); r3 = softplus_f(r3); }
            if (OUTBF) {
                unsigned u0 = (unsigned)f2bf(r0) | ((unsigned)f2bf(r1) << 16);
                unsigned u1 = (unsigned)f2bf(r2) | ((unsigned)f2bf(r3) << 16);
                uint2 val; val.x = u0; val.y = u1;
                unsigned short* Cb = (unsigned short*)C;
                *(uint2*)(Cb + (long)grow * NC + c0 + tx * 4) = val;
            } else {
                float4 o; o.x = r0; o.y = r1; o.z = r2; o.w = r3;
                *(float4*)(&C[(long)grow * NC + c0 + tx * 4]) = o;
            }
        }
    }
}

// WB[k][j], j=0..511: g=j&1 (0=f/Wf, 1=s/Ws); pos=j>>1; blk=pos>>7 (0=dst->x_i
// cols 0..127, 1=src->x_j cols 128..255); c=pos&127.
__global__ void build_WB(const float* __restrict__ Wf, const float* __restrict__ Ws,
                         float* __restrict__ WB) {
    int idx = blockIdx.x * blockDim.x + threadIdx.x;
    if (idx >= 128 * 512) return;
    int k = idx >> 9;
    int j = idx & 511;
    int g = j & 1;
    int pos = j >> 1;
    int blk = pos >> 7;
    int c = pos & 127;
    const float* W = g ? Ws : Wf;
    WB[idx] = W[c * ZDIM + blk * 128 + k];
}

// WE[l][g][c][k] bf16, k<41: edge-weight col, k==41: bias, else 0. K padded to 64.
__global__ void build_WE(const float* __restrict__ Wf, const float* __restrict__ Ws,
                         const float* __restrict__ bf, const float* __restrict__ bs,
                         unsigned short* __restrict__ WE) {
    int idx = blockIdx.x * blockDim.x + threadIdx.x;
    if (idx >= LL * 2 * 128 * 64) return;
    int k = idx & 63;
    int c = (idx >> 6) & 127;
    int g = (idx >> 13) & 1;
    int l = idx >> 14;
    const float* W = g ? Ws : Wf;
    const float* b = g ? bs : bf;
    float v = 0.f;
    if (k < FE) v = W[((long)l * 128 + c) * ZDIM + 256 + k];
    else if (k == FE) v = b[l * 128 + c];
    WE[idx] = f2bf(v);
}

// WT[Kpad][C] = W[C][K]^T zero-padded
__global__ void transpose_pad(const float* __restrict__ W, float* __restrict__ WT,
                              int C_, int K_, int Kpad) {
    int idx = blockIdx.x * blockDim.x + threadIdx.x;
    if (idx >= Kpad * C_) return;
    int k = idx / C_;
    int c = idx - k * C_;
    WT[idx] = (k < K_) ? W[c * K_ + k] : 0.f;
}

// ---------------------------------------------------------------------------
// Counting sort of edges by dst (static graph, reused for all 3 layers).
// ---------------------------------------------------------------------------
__global__ void hist_dst(const int* __restrict__ dstI, int* __restrict__ deg) {
    int idx = blockIdx.x * 256 + threadIdx.x;
    if (idx < EE) atomicAdd(&deg[dstI[idx]], 1);
}

__global__ void scan_block_sums(const int* __restrict__ deg, int* __restrict__ bsum) {
    __shared__ int sh[256];
    int i = blockIdx.x * 256 + threadIdx.x;
    sh[threadIdx.x] = (i < NN) ? deg[i] : 0;
    __syncthreads();
    for (int s = 128; s > 0; s >>= 1) {
        if (threadIdx.x < s) sh[threadIdx.x] += sh[threadIdx.x + s];
        __syncthreads();
    }
    if (threadIdx.x == 0) bsum[blockIdx.x] = sh[0];
}

__global__ void scan_partials_k(int* __restrict__ bsum, int nb) {
    __shared__ int sh[256];
    int t = threadIdx.x;
    int v = (t < nb) ? bsum[t] : 0;
    sh[t] = v;
    __syncthreads();
    for (int off = 1; off < 256; off <<= 1) {
        int u = (t >= off) ? sh[t - off] : 0;
        __syncthreads();
        sh[t] += u;
        __syncthreads();
    }
    if (t < nb) bsum[t] = sh[t] - v;   // exclusive block offsets
}

__global__ void scan_apply(const int* __restrict__ deg, const int* __restrict__ bsum,
                           int* __restrict__ rowptr, int* __restrict__ cursor) {
    __shared__ int sh[256];
    int i = blockIdx.x * 256 + threadIdx.x;
    int t = threadIdx.x;
    int v = (i < NN) ? deg[i] : 0;
    int orig = v;
    sh[t] = v;
    __syncthreads();
    for (int off = 1; off < 256; off <<= 1) {
        int u = (t >= off) ? sh[t - off] : 0;
        __syncthreads();
        sh[t] += u;
        __syncthreads();
    }
    int ex = sh[t] - orig + bsum[blockIdx.x];
    if (i < NN) { rowptr[i] = ex; cursor[i] = ex; }
    if (i == NN - 1) rowptr[NN] = ex + orig;   // == EE
}

// srcS[p] = src id of slot p; eOf[p] = original edge index of slot p.
__global__ void scatter_edges(const int* __restrict__ srcI, const int* __restrict__ dstI,
                              int* __restrict__ cursor, int* __restrict__ srcS,
                              int* __restrict__ eOf) {
    int idx = blockIdx.x * 256 + threadIdx.x;
    if (idx >= EE) return;
    int d = dstI[idx];
    int p = atomicAdd(&cursor[d], 1);
    srcS[p] = srcI[idx];
    eOf[p] = idx;
}

// eaB[slot][48] bf16 A-fragment rows in dst-sorted order: k<41 = ea, k==41 = 1.0
// (bias), 42..47 = 0. Gather-read (random 164B rows), coalesced sequential write.
__global__ void pack_ea(const float* __restrict__ ea, const int* __restrict__ eOf,
                        unsigned* __restrict__ eaBu) {
    int idx = blockIdx.x * 256 + threadIdx.x;
    if (idx >= EE * 24) return;
    int p = idx / 24;
    int k2 = idx - p * 24;
    int k = k2 * 2;
    int e = eOf[p];
    const float* row = ea + (long)e * FE;
    float v0 = 0.f, v1 = 0.f;
    if (k < FE) v0 = row[k];
    if (k + 1 < FE) v1 = row[k + 1];
    else if (k + 1 == FE) v1 = 1.0f;
    eaBu[idx] = (unsigned)f2bf(v0) | ((unsigned)f2bf(v1) << 16);
}

// ---------------------------------------------------------------------------
// Per-dst-node fused edge kernel, v5.
// Channel permutation: MFMA tile nt, lane l16 owns channel
//   c(nt,l16) = l16*4 + (nt&3) + 64*(nt>>2)
// (free choice of B-row assignment). This makes every per-lane src/dst access
// a CONTIGUOUS uint4 (4 adjacent channels), so:
//   - dst projection  = 2 x uint4 loads
//   - per-r src gather = 2 x uint4 loads (256B contiguous per quad)
//   - final store      = float4 per lane (quads 0/1)
// Gathers for the whole chunk are staged up-front (8 uint4 = 32 VGPR) for MLP;
// per-nt MFMAs consume immediately -> NO accf[8]/accs[8] arrays (the 64-VGPR
// pressure driver of R1-R4). Plain __launch_bounds__(256): the min-occupancy
// clause forced 84-VGPR spills in R2/R3. Target: <=128 VGPR -> 4 waves/SIMD.
// ---------------------------------------------------------------------------
__global__ __launch_bounds__(256)
void edge_node(const unsigned* __restrict__ Pu,             // [N][256] uint pairs
               const unsigned short* __restrict__ eaB,      // [E+16][48] bf16 sorted
               const int* __restrict__ srcS,                // [E+16] sorted src ids
               const int* __restrict__ rowptr,              // [N+1]
               const unsigned short* __restrict__ WE,       // [2][128][64] this layer
               float* __restrict__ out) {
    const int lane = threadIdx.x & 63;
    const int quad = lane >> 4;
    const int l16 = lane & 15;
    const int nW = gridDim.x * 4;
    const unsigned short* WEf = WE;
    const unsigned short* WEs = WE + 128 * 64;

    for (int n = blockIdx.x * 4 + (threadIdx.x >> 6); n < NN; n += nW) {
        int r0 = rowptr[n], r1 = rowptr[n + 1];

        // dst projection (x_i term): channels l16*4+{0..3} and 64+l16*4+{0..3}
        const uint4* pdr = (const uint4*)(Pu + (size_t)n * 256);
        uint4 pdA = pdr[l16];
        uint4 pdB = pdr[16 + l16];

        float aggv[8];
#pragma unroll
        for (int nt = 0; nt < 8; nt++) aggv[nt] = 0.f;

        for (int base = r0; base < r1; base += 16) {
            int rows = r1 - base;
            if (rows > 16) rows = 16;

            const unsigned short* ar = eaB + (size_t)(base + l16) * 48;
            s8v a0 = *(const s8v*)(ar + quad * 8);                 // k = 0..31
            s8v a1 = {0, 0, 0, 0, 0, 0, 0, 0};
            if (quad < 2) a1 = *(const s8v*)(ar + 32 + quad * 8);  // k = 32..47
            int s16 = srcS[base + l16];

            // stage ALL src gathers for this chunk (wide, contiguous, in flight
            // together). quad q, reg r -> edge q*4+r -> row sv.
            uint4 puA[4], puB[4];
#pragma unroll
            for (int r = 0; r < 4; r++) {
                int sv = __shfl(s16, quad * 4 + r);
                const uint4* ps = (const uint4*)(Pu + (size_t)sv * 256 + 128);
                puA[r] = ps[l16];
                puB[r] = ps[16 + l16];
            }

            // per channel-tile: 4 MFMAs (dst folded into C-init) + immediate gate
#pragma unroll
            for (int nt = 0; nt < 8; nt++) {
                const int hi = nt >> 2;
                const int j4 = nt & 3;
                int crow = l16 * 4 + j4 + (hi << 6);
                unsigned pdu = hi ? u4c(pdB, j4) : u4c(pdA, j4);
                float fdf = bflo2f(pdu);
                float fds = bfhi2f(pdu);
                f4v zf = {fdf, fdf, fdf, fdf};
                f4v zs = {fds, fds, fds, fds};
                s8v bf0 = *(const s8v*)(WEf + crow * 64 + quad * 8);
                s8v bf1 = *(const s8v*)(WEf + crow * 64 + 32 + quad * 8);
                zf = __builtin_amdgcn_mfma_f32_16x16x32_bf16(a0, bf0, zf, 0, 0, 0);
                zf = __builtin_amdgcn_mfma_f32_16x16x32_bf16(a1, bf1, zf, 0, 0, 0);
                s8v bs0 = *(const s8v*)(WEs + crow * 64 + quad * 8);
                s8v bs1 = *(const s8v*)(WEs + crow * 64 + 32 + quad * 8);
                zs = __builtin_amdgcn_mfma_f32_16x16x32_bf16(a0, bs0, zs, 0, 0, 0);
                zs = __builtin_amdgcn_mfma_f32_16x16x32_bf16(a1, bs1, zs, 0, 0, 0);
#pragma unroll
                for (int r = 0; r < 4; r++) {
                    unsigned u = hi ? u4c(puB[r], j4) : u4c(puA[r], j4);
                    float f = zf[r] + bflo2f(u);
                    float s = zs[r] + bfhi2f(u);
                    float m = sigmoid_f(f) * softplus_f(s);
                    aggv[nt] += (quad * 4 + r < rows) ? m : 0.f;
                }
            }
        }

        // cross-quad reduce: sum the 16 edge rows per channel
#pragma unroll
        for (int nt = 0; nt < 8; nt++) {
            float v = aggv[nt];
            v += __shfl_xor(v, 16);
            v += __shfl_xor(v, 32);
            aggv[nt] = v;
        }
        // fused residual + softplus; lane l16 owns 4 adjacent channels -> float4
        float* orow = out + (size_t)n * CC;
        if (quad == 0) {
            float4 o = *(const float4*)(orow + l16 * 4);
            o.x = softplus_f(o.x + aggv[0]);
            o.y = softplus_f(o.y + aggv[1]);
            o.z = softplus_f(o.z + aggv[2]);
            o.w = softplus_f(o.w + aggv[3]);
            *(float4*)(orow + l16 * 4) = o;
        } else if (quad == 1) {
            float4 o = *(const float4*)(orow + 64 + l16 * 4);
            o.x = softplus_f(o.x + aggv[4]);
            o.y = softplus_f(o.y + aggv[5]);
            o.z = softplus_f(o.z + aggv[6]);
            o.w = softplus_f(o.w + aggv[7]);
            *(float4*)(orow + 64 + l16 * 4) = o;
        }
    }
}

__global__ void pool_accum(const float* __restrict__ post, const int* __restrict__ batch,
                           float* __restrict__ sums, float* __restrict__ cnt) {
    int idx = blockIdx.x * blockDim.x + threadIdx.x;
    if (idx >= NN * CC) return;
    int n = idx >> 7;
    int c = idx & 127;
    int g = batch[n];
    atomicAdd(&sums[g * CC + c], post[idx]);
    if (c == 0) atomicAdd(&cnt[g], 1.0f);
}

__global__ void pool_head(const float* __restrict__ sums, const float* __restrict__ cnt,
                          const float* __restrict__ Wout, const float* __restrict__ bout,
                          float* __restrict__ y) {
    int g = blockIdx.x;
    int c = threadIdx.x;  // 128
    float v = sums[g * CC + c] / fmaxf(cnt[g], 1.0f) * Wout[c];
#pragma unroll
    for (int off = 32; off > 0; off >>= 1) v += __shfl_down(v, off);
    __shared__ float red[2];
    if ((c & 63) == 0) red[c >> 6] = v;
    __syncthreads();
    if (c == 0) y[g] = red[0] + red[1] + bout[0];
}

extern "C" void kernel_launch(void* const* d_in, const int* in_sizes, int n_in,
                              void* d_out, int out_size, void* d_ws, size_t ws_size,
                              hipStream_t stream) {
    const float* x      = (const float*)d_in[0];
    const int*   eidx   = (const int*)d_in[1];
    const float* ea     = (const float*)d_in[2];
    const int*   batch  = (const int*)d_in[3];
    const float* W_pre  = (const float*)d_in[4];
    const float* b_pre  = (const float*)d_in[5];
    const float* Wf     = (const float*)d_in[6];
    const float* bf     = (const float*)d_in[7];
    const float* Ws     = (const float*)d_in[8];
    const float* bs     = (const float*)d_in[9];
    const float* W_post = (const float*)d_in[10];
    const float* b_post = (const float*)d_in[11];
    const float* W_out  = (const float*)d_in[12];
    const float* b_out  = (const float*)d_in[13];
    float* y = (float*)d_out;

    const int* srcI = eidx;        // edge_index[0] = src (x_j)
    const int* dstI = eidx + EE;   // edge_index[1] = dst (x_i)

    // workspace layout (~245 MB)
    char* wp = (char*)d_ws;
    unsigned short* P_bf = (unsigned short*)wp; wp += (size_t)NN * 512 * 2;   // 51.2MB
    unsigned short* eaB  = (unsigned short*)wp; wp += (size_t)(EE + 16) * 48 * 2; // 153.6MB
    int* srcS   = (int*)wp; wp += (size_t)(EE + 16) * 4;                      // 6.4MB
    int* eOf    = (int*)wp; wp += (size_t)EE * 4;                             // 6.4MB
    float* out  = (float*)wp; wp += (size_t)NN * CC * 4;                      // 25.6MB
    float* WB   = (float*)wp; wp += 128 * 512 * 4;
    float* WT   = (float*)wp; wp += 128 * 128 * 4;
    float* sums = (float*)wp; wp += (size_t)GG * CC * 4;
    float* cnt  = (float*)wp; wp += GG * 4;
    unsigned short* WE = (unsigned short*)wp; wp += (size_t)LL * 2 * 128 * 64 * 2;
    int* deg    = (int*)wp; wp += (size_t)NN * 4;
    int* rowptr = (int*)wp; wp += (size_t)(NN + 1) * 4;
    int* cursor = (int*)wp; wp += (size_t)NN * 4;
    int* bsum   = (int*)wp; wp += 256 * 4;
    float* post = (float*)P_bf;             // reuse after layers

    int rowTiles = (NN + 63) / 64;
    int scanBlocks = (NN + 255) / 256;      // 196

    // pre-FC
    transpose_pad<<<(96 * 128 + 255) / 256, 256, 0, stream>>>(W_pre, WT, CC, FN, 96);
    gemm_rt<1, 0><<<rowTiles, 256, 0, stream>>>(x, WT, out, b_pre, NN, FN, FN, CC);

    build_WE<<<(LL * 2 * 128 * 64 + 255) / 256, 256, 0, stream>>>(Wf, Ws, bf, bs, WE);

    // ---- counting sort by dst + A-fragment pack (once, reused 3 layers) ----
    hipMemsetAsync(deg, 0, (size_t)NN * 4, stream);
    hist_dst<<<(EE + 255) / 256, 256, 0, stream>>>(dstI, deg);
    scan_block_sums<<<scanBlocks, 256, 0, stream>>>(deg, bsum);
    scan_partials_k<<<1, 256, 0, stream>>>(bsum, scanBlocks);
    scan_apply<<<scanBlocks, 256, 0, stream>>>(deg, bsum, rowptr, cursor);
    scatter_edges<<<(EE + 255) / 256, 256, 0, stream>>>(srcI, dstI, cursor, srcS, eOf);
    hipMemsetAsync(srcS + EE, 0, 16 * 4, stream);                 // tail pad: node 0
    hipMemsetAsync(eaB + (size_t)EE * 48, 0, 16 * 48 * 2, stream);// tail pad: zeros
    pack_ea<<<(EE * 24 + 255) / 256, 256, 0, stream>>>(ea, eOf, (unsigned*)eaB);

    for (int l = 0; l < LL; l++) {
        const float* Wfl = Wf + (size_t)l * CC * ZDIM;
        const float* Wsl = Ws + (size_t)l * CC * ZDIM;
        build_WB<<<(128 * 512 + 255) / 256, 256, 0, stream>>>(Wfl, Wsl, WB);
        gemm_rt<0, 1><<<rowTiles * 4, 256, 0, stream>>>(out, WB, (float*)P_bf,
                                                        nullptr, NN, CC, CC, 512);
        edge_node<<<1024, 256, 0, stream>>>((const unsigned*)P_bf, eaB, srcS,
                                            rowptr, WE + (size_t)l * 2 * 128 * 64,
                                            out);
    }

    // post-FC
    transpose_pad<<<(128 * 128 + 255) / 256, 256, 0, stream>>>(W_post, WT, CC, CC, CC);
    gemm_rt<1, 0><<<rowTiles, 256, 0, stream>>>(out, WT, post, b_post, NN, CC, CC, CC);

    // global mean pool + head
    hipMemsetAsync(sums, 0, ((size_t)GG * CC + GG) * sizeof(float), stream);
    pool_accum<<<(NN * CC + 255) / 256, 256, 0, stream>>>(post, batch, sums, cnt);
    pool_head<<<GG, 128, 0, stream>>>(sums, cnt, W_out, b_out, y);
}